// Round 7
// baseline (125.339 us; speedup 1.0000x reference)
//
#include <hip/hip_runtime.h>

// B=8, Cin=64, H=W=128, Cout=64, 9 bilinear taps at (i+0.4, j+0.4) == exact 4x4
// conv with zero pad. Implicit GEMM, bf16 MFMA 32x32x16.
//
// v7: barrier-free conv.
//   - prep: x (NCHW fp32) -> xT[b][y'(132)][cq(8)][x'(132)][8ch] bf16, zero
//     borders (y'=gy+1, x'=gx+1). 17.8 MB in d_ws.
//   - conv: NO LDS, NO barriers. A-fragments read straight from xT: one
//     16B-aligned lane-dense 1KB wave-load each (L1/L2 hits; per-batch xT
//     2.2MB resident in the wg&7 XCD's L2). B from 128KB wb table.
//   - A and B in explicit distance-1 double-buffered register queues,
//     64-step loop fully unrolled.

#define CIN   64
#define COUT  64
#define HH    128
#define WW    128

typedef __attribute__((ext_vector_type(8)))  short bf16x8;   // 4 VGPRs
typedef __attribute__((ext_vector_type(4)))  float f32x4;
typedef __attribute__((ext_vector_type(16))) float f32x16;   // 32x32 acc
typedef __attribute__((ext_vector_type(4)))  unsigned int u32x4;

__device__ __forceinline__ unsigned short f2bf(float f) {
  unsigned int u = __float_as_uint(f);
  u = (u + 0x7fffu + ((u >> 16) & 1u)) >> 16;   // RNE
  return (unsigned short)u;
}

// ---------------------------------------------------------------------------
// W4[o][c][tap(r,s)] = sum_k w[o,c,k]*cy_k(r-iy_k)*cx_k(s-ix_k).
//   wb[((g*2+h8)*16 + rs8*2 + ni)*64 + lane)*8 + j]
// lane: o = ni*32 + (lane&31), ch = g*16 + (lane>>5)*8 + j, tap = h8*8 + rs8.
// (verified v4-v6: absmax 0.0156)
// ---------------------------------------------------------------------------
__global__ void make_wb(const float* __restrict__ wgt,
                        const float* __restrict__ off,
                        unsigned short* __restrict__ wb)
{
  int id = blockIdx.x * 64 + threadIdx.x;       // 4096 = 64*64
  int o = id >> 6, c = id & 63;
  float W16[16];
  #pragma unroll
  for (int i = 0; i < 16; ++i) W16[i] = 0.f;
  for (int k = 0; k < 9; ++k) {
    float dy = off[2*k], dx = off[2*k+1];
    float fyf = floorf(dy), fxf = floorf(dx);
    int   iy = (int)fyf,   ix = (int)fxf;       // in {0,1,2}
    float fy = dy - fyf,   fx = dx - fxf;
    float wk = wgt[(o*CIN + c)*9 + k];
    W16[(iy  )*4 + ix  ] += wk * (1.f-fy)*(1.f-fx);
    W16[(iy  )*4 + ix+1] += wk * (1.f-fy)*fx;
    W16[(iy+1)*4 + ix  ] += wk * fy*(1.f-fx);
    W16[(iy+1)*4 + ix+1] += wk * fy*fx;
  }
  int g = c >> 4, half = (c >> 3) & 1, j = c & 7;
  int ni = o >> 5, l31 = o & 31;
  int lane = half*32 + l31;
  for (int tap = 0; tap < 16; ++tap) {
    int h8 = tap >> 3, rs8 = tap & 7;
    wb[(size_t)((((g*2 + h8)*16) + rs8*2 + ni)*64 + lane)*8 + j] = f2bf(W16[tap]);
  }
}

// ---------------------------------------------------------------------------
// Transpose/pad: xT[((b*132 + yp)*8 + cq)*132 + xp] cell = 8 ch bf16 (16 B).
// yp = gy+1 (0..130; yp=131 unused), xp = gx+1 (0..131). Borders zero.
// ---------------------------------------------------------------------------
__global__ __launch_bounds__(128)
void transpose_x(const float* __restrict__ x, unsigned short* __restrict__ xt)
{
  const int bid = blockIdx.x;                 // 8 * 131
  const int b   = bid / 131;
  const int yp  = bid - b * 131;              // 0..130
  const int t   = threadIdx.x;                // 128

  unsigned short* rowbase = xt + (size_t)(b*132 + yp)*8*132*8;

  if (yp == 0 || yp >= 129) {                 // border row: all zeros
    for (int i = t; i < 8*132; i += 128)
      *(u32x4*)&rowbase[i*8] = (u32x4){0u,0u,0u,0u};
    return;
  }
  const int gy = yp - 1;
  const int px = t;                           // 0..127
  #pragma unroll
  for (int cq = 0; cq < 8; ++cq) {
    const float* ps = x + ((size_t)(b*CIN + cq*8)*HH + gy)*WW + px;
    float v[8];
    #pragma unroll
    for (int cc = 0; cc < 8; ++cc) v[cc] = ps[(size_t)cc*HH*WW];
    unsigned int pk[4];
    #pragma unroll
    for (int i = 0; i < 4; ++i)
      pk[i] = (unsigned int)f2bf(v[2*i]) | ((unsigned int)f2bf(v[2*i+1]) << 16);
    *(u32x4*)&rowbase[(cq*132 + px + 1)*8] = *(u32x4*)pk;
  }
  if (t < 32) {                               // zero cols 0,129,130,131 (8 cq x 4)
    int cq = t >> 2, csel = t & 3;
    int col = (csel == 0) ? 0 : (128 + csel);
    *(u32x4*)&rowbase[(cq*132 + col)*8] = (u32x4){0u,0u,0u,0u};
  }
}

// ---------------------------------------------------------------------------
// conv: block = 256 thr (4 waves), zero LDS, zero barriers.
// wave -> output row y0+wave, px x0..x0+63 (2 m-frags), all 64 Cout (2 n-frags).
// ---------------------------------------------------------------------------
__global__ __launch_bounds__(256, 2)
void conv_mfma(const unsigned short* __restrict__ xt,
               const unsigned short* __restrict__ wb,
               float* __restrict__ out)
{
  const int wg = blockIdx.x;                  // 512
  const int b  = wg & 7;                      // XCD = batch
  const int i6 = wg >> 3;                     // 0..63
  const int y0 = (i6 >> 1) * 4;
  const int x0 = (i6 & 1) * 64;
  const int t  = threadIdx.x;
  const int lane = t & 63;
  const int wave = t >> 6;                    // row
  const int l31  = lane & 31;
  const int half = lane >> 5;
  const int y    = y0 + wave;

  f32x16 acc[2][2];
  #pragma unroll
  for (int mi = 0; mi < 2; ++mi)
    #pragma unroll
    for (int ni = 0; ni < 2; ++ni)
      acc[mi][ni] = (f32x16)(0.f);

  const unsigned short* wl = wb + lane*8;

  // A addr: xt[(((b*132 + (y+r))*8 + (g*2+half))*132 + (x0 + mi*32 + l31 + s))*8]
  const unsigned short* xbase = xt + (size_t)(b*132 + y)*8*132*8
                                   + (size_t)(x0 + l31)*8 + (size_t)half*132*8;

  bf16x8 aq[2][2], bq[2][2];

  auto loadB = [&](int g, int tap, bf16x8 (&dst)[2]) {
    int h8 = tap >> 3, rs8 = tap & 7;
    #pragma unroll
    for (int ni = 0; ni < 2; ++ni)
      dst[ni] = *(const bf16x8*)(wl + (size_t)(((g*2 + h8)*16) + rs8*2 + ni)*512);
  };
  auto loadA = [&](int g, int tap, bf16x8 (&dst)[2]) {
    int r = tap >> 2, s = tap & 3;
    const unsigned short* p = xbase + (size_t)(r*8*132 + g*2*132 + s)*8;
    #pragma unroll
    for (int mi = 0; mi < 2; ++mi)
      dst[mi] = *(const bf16x8*)(p + mi*32*8);
  };

  loadA(0, 0, aq[0]);
  loadB(0, 0, bq[0]);

  #pragma unroll
  for (int g = 0; g < 4; ++g) {
    #pragma unroll
    for (int tap = 0; tap < 16; ++tap) {
      // prefetch next step (dist 1); slot (tap+1)&1 never collides with tap&1
      if (tap < 15) {
        loadA(g, tap + 1, aq[(tap + 1) & 1]);
        loadB(g, tap + 1, bq[(tap + 1) & 1]);
      } else if (g < 3) {
        loadA(g + 1, 0, aq[0]);
        loadB(g + 1, 0, bq[0]);
      }
      const int sl = tap & 1;
      #pragma unroll
      for (int mi = 0; mi < 2; ++mi) {
        acc[mi][0] = __builtin_amdgcn_mfma_f32_32x32x16_bf16(aq[sl][mi], bq[sl][0], acc[mi][0], 0, 0, 0);
        acc[mi][1] = __builtin_amdgcn_mfma_f32_32x32x16_bf16(aq[sl][mi], bq[sl][1], acc[mi][1], 0, 0, 0);
      }
    }
  }

  // ---- epilogue: D col = o (lane&31), row = (reg&3) + 8*(reg>>2) + 4*half ----
  #pragma unroll
  for (int mi = 0; mi < 2; ++mi) {
    #pragma unroll
    for (int ni = 0; ni < 2; ++ni) {
      int o = ni*32 + l31;
      float* dst = out + (((size_t)(b*COUT + o))*HH + y)*WW + x0 + mi*32 + 4*half;
      #pragma unroll
      for (int rg = 0; rg < 4; ++rg) {
        f32x4 v = (f32x4){acc[mi][ni][4*rg+0], acc[mi][ni][4*rg+1],
                          acc[mi][ni][4*rg+2], acc[mi][ni][4*rg+3]};
        *(f32x4*)(dst + 8*rg) = v;
      }
    }
  }
}

// ---------------------------------------------------------------------------
extern "C" void kernel_launch(void* const* d_in, const int* in_sizes, int n_in,
                              void* d_out, int out_size, void* d_ws, size_t ws_size,
                              hipStream_t stream)
{
  const float* x   = (const float*)d_in[0];   // [8,64,128,128] fp32
  const float* wgt = (const float*)d_in[1];   // [64,64,9] fp32
  const float* off = (const float*)d_in[2];   // [9,2] fp32
  float* out = (float*)d_out;                 // [8,64,128,128] fp32

  unsigned short* wb = (unsigned short*)d_ws;            // 128 KB weights
  unsigned short* xt = (unsigned short*)d_ws + 65536;    // 17.84 MB xT

  make_wb<<<64, 64, 0, stream>>>(wgt, off, wb);
  transpose_x<<<8*131, 128, 0, stream>>>(x, xt);
  conv_mfma<<<512, 256, 0, stream>>>(xt, wb, out);
}

// Round 8
// 120.852 us; speedup vs baseline: 1.0371x; 1.0371x over previous
//
#include <hip/hip_runtime.h>

// B=8, Cin=64, H=W=128, Cout=64, 9 bilinear taps at (i+0.4, j+0.4) == exact 4x4
// conv with zero pad. Implicit GEMM, bf16 MFMA 32x32x16.
//
// v8: async-DMA staging (global_load_lds) -- the compiler cannot serialize it.
//   - xT: bf16 NHWC-chunked [b][yp(132)][cq(8)][xp(136)] cells of 8ch=16B,
//     zero borders, XCD-aligned transpose (bid&7 = b).
//   - conv: stage 7x8x72-cell halo tile via 28 global_load_lds dwordx4 per
//     wave (no dest VGPRs), ONE syncthreads drain, then 64 unrolled MFMA
//     k-steps; only vmem in the loop = dist-2 B-stream (clean vmcnt FIFO).
//   - LDS 64512 B -> 2 blocks/CU; grid 512 co-resident.

#define CIN   64
#define COUT  64
#define HH    128
#define WW    128

typedef __attribute__((ext_vector_type(8)))  short bf16x8;   // 4 VGPRs
typedef __attribute__((ext_vector_type(4)))  float f32x4;
typedef __attribute__((ext_vector_type(16))) float f32x16;   // 32x32 acc
typedef __attribute__((ext_vector_type(4)))  unsigned int u32x4;

#define AS1C(p) ((const __attribute__((address_space(1))) unsigned int*)(p))
#define AS3P(p) ((__attribute__((address_space(3))) unsigned int*)(p))

__device__ __forceinline__ unsigned short f2bf(float f) {
  unsigned int u = __float_as_uint(f);
  u = (u + 0x7fffu + ((u >> 16) & 1u)) >> 16;   // RNE
  return (unsigned short)u;
}

// ---------------------------------------------------------------------------
// W4[o][c][tap(r,s)] = sum_k w[o,c,k]*cy_k(r-iy_k)*cx_k(s-ix_k).
//   wb[(((g*2+h8)*16) + rs8*2 + ni)*64 + lane)*8 + j]
// lane: o = ni*32 + (lane&31), ch = g*16 + (lane>>5)*8 + j, tap = h8*8 + rs8.
// (verified v4-v7: absmax 0.0156)
// ---------------------------------------------------------------------------
__global__ void make_wb(const float* __restrict__ wgt,
                        const float* __restrict__ off,
                        unsigned short* __restrict__ wb)
{
  int id = blockIdx.x * 64 + threadIdx.x;       // 4096 = 64*64
  int o = id >> 6, c = id & 63;
  float W16[16];
  #pragma unroll
  for (int i = 0; i < 16; ++i) W16[i] = 0.f;
  for (int k = 0; k < 9; ++k) {
    float dy = off[2*k], dx = off[2*k+1];
    float fyf = floorf(dy), fxf = floorf(dx);
    int   iy = (int)fyf,   ix = (int)fxf;       // in {0,1,2}
    float fy = dy - fyf,   fx = dx - fxf;
    float wk = wgt[(o*CIN + c)*9 + k];
    W16[(iy  )*4 + ix  ] += wk * (1.f-fy)*(1.f-fx);
    W16[(iy  )*4 + ix+1] += wk * (1.f-fy)*fx;
    W16[(iy+1)*4 + ix  ] += wk * fy*(1.f-fx);
    W16[(iy+1)*4 + ix+1] += wk * fy*fx;
  }
  int g = c >> 4, half = (c >> 3) & 1, j = c & 7;
  int ni = o >> 5, l31 = o & 31;
  int lane = half*32 + l31;
  for (int tap = 0; tap < 16; ++tap) {
    int h8 = tap >> 3, rs8 = tap & 7;
    wb[(size_t)((((g*2 + h8)*16) + rs8*2 + ni)*64 + lane)*8 + j] = f2bf(W16[tap]);
  }
}

// ---------------------------------------------------------------------------
// xT[((b*132 + yp)*8 + cq)*136 + xp] : cell = 8 ch bf16 = 16 B.
// yp = gy+1 (rows 0,129..131 zero), xp = gx+1 (cols 0,129..135 zero).
// bid&7 = b so writes land in the XCD L2 that conv (wg&7 = b) reads from.
// ---------------------------------------------------------------------------
__global__ __launch_bounds__(256)
void transpose_x(const float* __restrict__ x, unsigned short* __restrict__ xt)
{
  const int bid = blockIdx.x;                 // 1056 = 132 * 8
  const int b   = bid & 7;
  const int yp  = bid >> 3;                   // 0..131
  const int t   = threadIdx.x;

  unsigned short* rowb = xt + (size_t)((b*132 + yp)*8)*136*8;

  if (yp == 0 || yp >= 129) {                 // border rows: all zero
    for (int i = t; i < 8*136; i += 256)
      *(u32x4*)&rowb[(size_t)i*8] = (u32x4){0u,0u,0u,0u};
    return;
  }
  const int gy  = yp - 1;
  const int cq  = t >> 5;                     // 0..7
  const int seg = t & 31;                     // float4 segment of the row
  const f32x4* ps = (const f32x4*)(x + ((size_t)(b*CIN + cq*8)*HH + gy)*WW) + seg;
  f32x4 v[8];
  #pragma unroll
  for (int cc = 0; cc < 8; ++cc) v[cc] = ps[(size_t)cc*(HH*WW/4)];
  #pragma unroll
  for (int u = 0; u < 4; ++u) {
    unsigned int pk[4];
    #pragma unroll
    for (int i = 0; i < 4; ++i)
      pk[i] = (unsigned int)f2bf(v[2*i][u]) | ((unsigned int)f2bf(v[2*i+1][u]) << 16);
    *(u32x4*)&rowb[(size_t)(cq*136 + seg*4 + u + 1)*8] = *(u32x4*)pk;
  }
  if (t < 64) {                               // zero cols 0,129..135 per cq
    int c2 = t >> 3, ci = t & 7;
    int col = ci ? (128 + ci) : 0;
    *(u32x4*)&rowb[(size_t)(c2*136 + col)*8] = (u32x4){0u,0u,0u,0u};
  }
}

// ---------------------------------------------------------------------------
constexpr int LC = 72;                        // cells per (row,cq) line

__global__ __launch_bounds__(256, 2)
void conv_mfma(const unsigned short* __restrict__ xt,
               const unsigned short* __restrict__ wb,
               float* __restrict__ out)
{
  __shared__ unsigned short lds[7*8*LC*8];    // 4032 cells * 16 B = 64512 B

  const int wg = blockIdx.x;                  // 512
  const int b  = wg & 7;                      // XCD = batch
  const int i6 = wg >> 3;                     // 0..63
  const int y0 = (i6 >> 1) * 4;
  const int x0 = (i6 & 1) * 64;
  const int t  = threadIdx.x;
  const int lane = t & 63;
  const int wave = t >> 6;                    // 0..3 = output row
  const int l31  = lane & 31;
  const int half = lane >> 5;
  const int y    = y0 + wave;

  // ---- async stage: 56 lines x 72 cells; 2 DMA issues per line per wave ----
  // load1: cells 0..63; load2: cells 4..67 (double-covers 4..63, harmless).
  #pragma unroll
  for (int i = 0; i < 14; ++i) {
    int l   = wave*14 + i;                    // 0..55
    int row = l >> 3, cq = l & 7;
    const unsigned short* gp = xt
        + ((size_t)((b*132 + y0 + row)*8 + cq)*136 + x0)*8 + (size_t)lane*8;
    unsigned short* lp = lds + (size_t)((row*8 + cq)*LC)*8;
    __builtin_amdgcn_global_load_lds(AS1C(gp),      AS3P(lp),      16, 0, 0);
    __builtin_amdgcn_global_load_lds(AS1C(gp + 32), AS3P(lp + 32), 16, 0, 0);
  }
  __syncthreads();                            // single drain + barrier

  // ---- compute: 64 unrolled k-steps; only vmem = dist-2 B stream ----
  f32x16 acc[2][2];
  #pragma unroll
  for (int mi = 0; mi < 2; ++mi)
    #pragma unroll
    for (int ni = 0; ni < 2; ++ni)
      acc[mi][ni] = (f32x16)(0.f);

  const unsigned short* wl = wb + lane*8;
  bf16x8 bq[3][2];
  auto loadB = [&](int ki, bf16x8 (&d)[2]) {
    int g = ki >> 4, tap = ki & 15;
    int h8 = tap >> 3, rs8 = tap & 7;
    #pragma unroll
    for (int ni = 0; ni < 2; ++ni)
      d[ni] = *(const bf16x8*)(wl + (size_t)(((g*2 + h8)*16) + rs8*2 + ni)*512);
  };
  loadB(0, bq[0]);
  loadB(1, bq[1]);

  #pragma unroll
  for (int ki = 0; ki < 64; ++ki) {
    if (ki < 62) loadB(ki + 2, bq[(ki + 2) % 3]);
    const int g = ki >> 4, tap = ki & 15;
    const int r = tap >> 2, s = tap & 3;
    bf16x8 afr[2];
    #pragma unroll
    for (int mi = 0; mi < 2; ++mi)
      afr[mi] = *(const bf16x8*)
        &lds[(size_t)(((wave + r)*8 + g*2 + half)*LC + (mi*32 + l31 + s))*8];
    #pragma unroll
    for (int mi = 0; mi < 2; ++mi) {
      acc[mi][0] = __builtin_amdgcn_mfma_f32_32x32x16_bf16(afr[mi], bq[ki % 3][0], acc[mi][0], 0, 0, 0);
      acc[mi][1] = __builtin_amdgcn_mfma_f32_32x32x16_bf16(afr[mi], bq[ki % 3][1], acc[mi][1], 0, 0, 0);
    }
  }

  // ---- epilogue: D col = o (lane&31), row = (reg&3) + 8*(reg>>2) + 4*half ----
  #pragma unroll
  for (int mi = 0; mi < 2; ++mi) {
    #pragma unroll
    for (int ni = 0; ni < 2; ++ni) {
      int o = ni*32 + l31;
      float* dst = out + (((size_t)(b*COUT + o))*HH + y)*WW + x0 + mi*32 + 4*half;
      #pragma unroll
      for (int rg = 0; rg < 4; ++rg) {
        f32x4 v = (f32x4){acc[mi][ni][4*rg+0], acc[mi][ni][4*rg+1],
                          acc[mi][ni][4*rg+2], acc[mi][ni][4*rg+3]};
        *(f32x4*)(dst + 8*rg) = v;
      }
    }
  }
}

// ---------------------------------------------------------------------------
extern "C" void kernel_launch(void* const* d_in, const int* in_sizes, int n_in,
                              void* d_out, int out_size, void* d_ws, size_t ws_size,
                              hipStream_t stream)
{
  const float* x   = (const float*)d_in[0];   // [8,64,128,128] fp32
  const float* wgt = (const float*)d_in[1];   // [64,64,9] fp32
  const float* off = (const float*)d_in[2];   // [9,2] fp32
  float* out = (float*)d_out;                 // [8,64,128,128] fp32

  unsigned short* wb = (unsigned short*)d_ws;           // 128 KB weights
  unsigned short* xt = (unsigned short*)d_ws + 65536;   // 18.4 MB xT

  make_wb<<<64, 64, 0, stream>>>(wgt, off, wb);
  transpose_x<<<1056, 256, 0, stream>>>(x, xt);
  conv_mfma<<<512, 256, 0, stream>>>(xt, wb, out);
}